// Round 2
// baseline (59.629 us; speedup 1.0000x reference)
//
#include <hip/hip_runtime.h>

// YOLO loss on (B,7,7,30) fp32 pred/target -> scalar.
// Memory-bound. Fix vs R0: coalesced global->LDS staging via
// global_load_lds (width 16), then per-cell LDS reads. R0 was TA-bound
// (stride-120B per-lane AoS loads = 64 lines per VMEM instruction).

#define NC 30
#define CPB 256                        // cells per block
#define TILE_FLOATS (CPB * NC)         // 7680 floats = 30720 B
#define CHUNKS ((TILE_FLOATS * 4) / 1024)  // 30 x 1KB wave-chunks

__device__ __forceinline__ float sq(float x) { return x * x; }

__device__ __forceinline__ void make_box(float cx, float cy, float w, float h,
                                         float jf, float kf, float b[4]) {
    float x = (cx + jf) * (1.0f / 7.0f);
    float y = (cy + kf) * (1.0f / 7.0f);
    b[0] = x - w * 0.5f;
    b[1] = y - h * 0.5f;
    b[2] = x + w * 0.5f;
    b[3] = y + h * 0.5f;
}

__device__ __forceinline__ float iou(const float a[4], const float b[4]) {
    float ix1 = fmaxf(a[0], b[0]);
    float iy1 = fmaxf(a[1], b[1]);
    float ix2 = fminf(a[2], b[2]);
    float iy2 = fminf(a[3], b[3]);
    float iw = fmaxf(ix2 - ix1, 0.0f);
    float ih = fmaxf(iy2 - iy1, 0.0f);
    float inter = iw * ih;
    float area_a = (a[2] - a[0]) * (a[3] - a[1]);
    float area_b = (b[2] - b[0]) * (b[3] - b[1]);
    return inter > 0.0f ? inter / (area_a + area_b - inter) : 0.0f;
}

// loss for one cell given pointers to its 30 pred / 30 targ floats
__device__ __forceinline__ float cell_loss(const float* __restrict__ P,
                                           const float* __restrict__ T,
                                           float jf, float kf) {
    float b1[4], b2[4], tb[4];
    make_box(P[0], P[1], P[2], P[3], jf, kf, b1);
    make_box(P[5], P[6], P[7], P[8], jf, kf, b2);
    make_box(T[0], T[1], T[2], T[3], jf, kf, tb);

    float i1 = iou(b1, tb);
    float i2 = iou(b2, tb);

    bool obj = T[4] > 0.0f;
    bool pick1 = i1 >= i2;

    float cls = 0.0f;
#pragma unroll
    for (int e = 10; e < 30; ++e) {
        float d = P[e] - T[e];
        cls += d * d;
    }

    float coo1 = 5.0f * (sq(P[0] - T[0]) + sq(P[1] - T[1]) +
                         sq(sqrtf(P[2]) - sqrtf(T[2])) +
                         sq(sqrtf(P[3]) - sqrtf(T[3]))) +
                 sq(P[4] - i1);
    float non1 = 0.5f * sq(P[4] - i2);

    float coo2 = 5.0f * (sq(P[5] - T[5]) + sq(P[6] - T[6]) +
                         sq(sqrtf(P[7]) - sqrtf(T[7])) +
                         sq(sqrtf(P[8]) - sqrtf(T[8]))) +
                 sq(P[9] - i2);
    float non2 = 0.5f * sq(P[9] - i1);

    float noobj = 0.5f * (P[4] * P[4] + P[9] * P[9]);

    float resp = pick1 ? (coo1 + non1) : (coo2 + non2);
    return obj ? (resp + cls) : noobj;
}

__global__ __launch_bounds__(256) void yolo_loss_kernel(
    const float* __restrict__ pred, const float* __restrict__ targ,
    float* __restrict__ out, int ncells, float inv_b) {
    __shared__ float sp[TILE_FLOATS];
    __shared__ float st[TILE_FLOATS];

    int t = threadIdx.x;
    int wave = t >> 6;
    int lane = t & 63;
    int base = blockIdx.x * CPB;
    int cell = base + t;

    bool full_tile = (base + CPB) <= ncells;  // uniform per block

    float loss = 0.0f;

    if (full_tile) {
        const float* pbase = pred + (size_t)base * NC;
        const float* tbase = targ + (size_t)base * NC;

        // Stage 30 KB per tensor: 30 chunks of 1 KB; wave w takes chunks
        // w, w+4, ... LDS dest is wave-uniform (+HW lane*16); global src
        // is per-lane contiguous -> fully coalesced dwordx4.
        for (int c = wave; c < CHUNKS; c += 4) {
            const float* gp = pbase + c * 256 + lane * 4;
            const float* gt = tbase + c * 256 + lane * 4;
            __builtin_amdgcn_global_load_lds(
                (const __attribute__((address_space(1))) unsigned int*)gp,
                (__attribute__((address_space(3))) unsigned int*)(sp + c * 256),
                16, 0, 0);
            __builtin_amdgcn_global_load_lds(
                (const __attribute__((address_space(1))) unsigned int*)gt,
                (__attribute__((address_space(3))) unsigned int*)(st + c * 256),
                16, 0, 0);
        }
        __syncthreads();  // drains vmcnt

        const float* P = sp + t * NC;
        const float* T = st + t * NC;
        int jc = (cell / 7) % 7;
        int kc = cell % 7;
        loss = cell_loss(P, T, (float)jc, (float)kc);
    } else if (cell < ncells) {
        // tail block (not hit for B=16384, kept for correctness)
        float P[NC], T[NC];
        const float* pp = pred + (size_t)cell * NC;
        const float* tt = targ + (size_t)cell * NC;
#pragma unroll
        for (int e = 0; e < NC; ++e) {
            P[e] = pp[e];
            T[e] = tt[e];
        }
        int jc = (cell / 7) % 7;
        int kc = cell % 7;
        loss = cell_loss(P, T, (float)jc, (float)kc);
    }

    // wave-64 reduction
#pragma unroll
    for (int off = 32; off > 0; off >>= 1) loss += __shfl_down(loss, off);

    __shared__ float wsum[4];
    int wid = threadIdx.x >> 6;
    if (lane == 0) wsum[wid] = loss;
    __syncthreads();

    if (threadIdx.x == 0) {
        float s = wsum[0] + wsum[1] + wsum[2] + wsum[3];
        atomicAdd(out, s * inv_b);
    }
}

extern "C" void kernel_launch(void* const* d_in, const int* in_sizes, int n_in,
                              void* d_out, int out_size, void* d_ws, size_t ws_size,
                              hipStream_t stream) {
    const float* pred = (const float*)d_in[0];
    const float* targ = (const float*)d_in[1];
    float* out = (float*)d_out;

    int ncells = in_sizes[0] / NC;  // B*7*7
    int batch = ncells / 49;        // B
    float inv_b = 1.0f / (float)batch;

    hipMemsetAsync(out, 0, sizeof(float), stream);

    int grid = (ncells + CPB - 1) / CPB;
    yolo_loss_kernel<<<grid, CPB, 0, stream>>>(pred, targ, out, ncells, inv_b);
}

// Round 3
// 36.186 us; speedup vs baseline: 1.6478x; 1.6478x over previous
//
#include <hip/hip_runtime.h>

// YOLO loss on (B,7,7,30) fp32 pred/target -> scalar.
// R2 diagnosis: R0/R1 both serialized on 3136 same-address atomicAdds
// (WRITE_SIZE ~= 3136*32B). Fix: block partials -> d_ws, second reduce
// kernel. Also CPB=128 (30.7KB LDS -> 5 blocks/CU) for load staggering.

#define NC 30
#define CPB 128                 // cells per block == threads per block
#define TILE_DW (CPB * NC)      // 3840 dwords = 15360 B per tensor
#define CHUNKS 15               // 1KB wave-chunks per tensor

__device__ __forceinline__ float sq(float x) { return x * x; }

__device__ __forceinline__ void make_box(float cx, float cy, float w, float h,
                                         float jf, float kf, float b[4]) {
    float x = (cx + jf) * (1.0f / 7.0f);
    float y = (cy + kf) * (1.0f / 7.0f);
    b[0] = x - w * 0.5f;
    b[1] = y - h * 0.5f;
    b[2] = x + w * 0.5f;
    b[3] = y + h * 0.5f;
}

__device__ __forceinline__ float iou(const float a[4], const float b[4]) {
    float ix1 = fmaxf(a[0], b[0]);
    float iy1 = fmaxf(a[1], b[1]);
    float ix2 = fminf(a[2], b[2]);
    float iy2 = fminf(a[3], b[3]);
    float iw = fmaxf(ix2 - ix1, 0.0f);
    float ih = fmaxf(iy2 - iy1, 0.0f);
    float inter = iw * ih;
    float area_a = (a[2] - a[0]) * (a[3] - a[1]);
    float area_b = (b[2] - b[0]) * (b[3] - b[1]);
    return inter > 0.0f ? inter / (area_a + area_b - inter) : 0.0f;
}

__device__ __forceinline__ float cell_loss(const float* __restrict__ P,
                                           const float* __restrict__ T,
                                           float jf, float kf) {
    float b1[4], b2[4], tb[4];
    make_box(P[0], P[1], P[2], P[3], jf, kf, b1);
    make_box(P[5], P[6], P[7], P[8], jf, kf, b2);
    make_box(T[0], T[1], T[2], T[3], jf, kf, tb);

    float i1 = iou(b1, tb);
    float i2 = iou(b2, tb);

    bool obj = T[4] > 0.0f;
    bool pick1 = i1 >= i2;

    float cls = 0.0f;
#pragma unroll
    for (int e = 10; e < 30; ++e) {
        float d = P[e] - T[e];
        cls += d * d;
    }

    float coo1 = 5.0f * (sq(P[0] - T[0]) + sq(P[1] - T[1]) +
                         sq(sqrtf(P[2]) - sqrtf(T[2])) +
                         sq(sqrtf(P[3]) - sqrtf(T[3]))) +
                 sq(P[4] - i1);
    float non1 = 0.5f * sq(P[4] - i2);

    float coo2 = 5.0f * (sq(P[5] - T[5]) + sq(P[6] - T[6]) +
                         sq(sqrtf(P[7]) - sqrtf(T[7])) +
                         sq(sqrtf(P[8]) - sqrtf(T[8]))) +
                 sq(P[9] - i2);
    float non2 = 0.5f * sq(P[9] - i1);

    float noobj = 0.5f * (P[4] * P[4] + P[9] * P[9]);

    float resp = pick1 ? (coo1 + non1) : (coo2 + non2);
    return obj ? (resp + cls) : noobj;
}

template <bool USE_WS>
__global__ __launch_bounds__(CPB) void yolo_partial_kernel(
    const float* __restrict__ pred, const float* __restrict__ targ,
    float* __restrict__ dst, int ncells, float scale) {
    __shared__ float sp[TILE_DW];
    __shared__ float st[TILE_DW];

    int t = threadIdx.x;
    int wave = t >> 6;
    int lane = t & 63;
    int base = blockIdx.x * CPB;
    int cell = base + t;

    bool full_tile = (base + CPB) <= ncells;

    float loss = 0.0f;

    if (full_tile) {
        const float* pbase = pred + (size_t)base * NC;
        const float* tbase = targ + (size_t)base * NC;

        // 15 x 1KB chunks per tensor; wave w takes chunks w, w+2, ...
        // LDS dest wave-uniform linear, global src per-lane contiguous.
        for (int c = wave; c < CHUNKS; c += 2) {
            __builtin_amdgcn_global_load_lds(
                (const __attribute__((address_space(1))) unsigned int*)(pbase + c * 256 + lane * 4),
                (__attribute__((address_space(3))) unsigned int*)(sp + c * 256),
                16, 0, 0);
            __builtin_amdgcn_global_load_lds(
                (const __attribute__((address_space(1))) unsigned int*)(tbase + c * 256 + lane * 4),
                (__attribute__((address_space(3))) unsigned int*)(st + c * 256),
                16, 0, 0);
        }
        __syncthreads();  // drains vmcnt; data visible to both waves

        int jc = (cell / 7) % 7;
        int kc = cell % 7;
        loss = cell_loss(sp + t * NC, st + t * NC, (float)jc, (float)kc);
    } else if (cell < ncells) {
        float P[NC], T[NC];
        const float* pp = pred + (size_t)cell * NC;
        const float* tt = targ + (size_t)cell * NC;
#pragma unroll
        for (int e = 0; e < NC; ++e) {
            P[e] = pp[e];
            T[e] = tt[e];
        }
        int jc = (cell / 7) % 7;
        int kc = cell % 7;
        loss = cell_loss(P, T, (float)jc, (float)kc);
    }

    // wave-64 reduction
#pragma unroll
    for (int off = 32; off > 0; off >>= 1) loss += __shfl_down(loss, off);

    __shared__ float wsum[CPB / 64];
    if (lane == 0) wsum[wave] = loss;
    __syncthreads();

    if (t == 0) {
        float s = 0.0f;
#pragma unroll
        for (int w = 0; w < CPB / 64; ++w) s += wsum[w];
        if (USE_WS) {
            dst[blockIdx.x] = s * scale;  // plain store, no atomic
        } else {
            atomicAdd(dst, s * scale);    // fallback if ws too small
        }
    }
}

__global__ __launch_bounds__(1024) void reduce_kernel(
    const float* __restrict__ ws, float* __restrict__ out, int n) {
    float s = 0.0f;
    for (int i = threadIdx.x; i < n; i += 1024) s += ws[i];
#pragma unroll
    for (int off = 32; off > 0; off >>= 1) s += __shfl_down(s, off);

    __shared__ float acc[16];
    int wave = threadIdx.x >> 6;
    int lane = threadIdx.x & 63;
    if (lane == 0) acc[wave] = s;
    __syncthreads();

    if (threadIdx.x == 0) {
        float tot = 0.0f;
#pragma unroll
        for (int w = 0; w < 16; ++w) tot += acc[w];
        out[0] = tot;
    }
}

extern "C" void kernel_launch(void* const* d_in, const int* in_sizes, int n_in,
                              void* d_out, int out_size, void* d_ws, size_t ws_size,
                              hipStream_t stream) {
    const float* pred = (const float*)d_in[0];
    const float* targ = (const float*)d_in[1];
    float* out = (float*)d_out;

    int ncells = in_sizes[0] / NC;  // B*7*7
    int batch = ncells / 49;        // B
    float inv_b = 1.0f / (float)batch;

    int grid = (ncells + CPB - 1) / CPB;

    if (ws_size >= (size_t)grid * sizeof(float)) {
        float* ws = (float*)d_ws;
        yolo_partial_kernel<true><<<grid, CPB, 0, stream>>>(pred, targ, ws,
                                                            ncells, inv_b);
        reduce_kernel<<<1, 1024, 0, stream>>>(ws, out, grid);
    } else {
        hipMemsetAsync(out, 0, sizeof(float), stream);
        yolo_partial_kernel<false><<<grid, CPB, 0, stream>>>(pred, targ, out,
                                                             ncells, inv_b);
    }
}